// Round 4
// baseline (631.046 us; speedup 1.0000x reference)
//
#include <hip/hip_runtime.h>
#include <cstdint>
#include <cstddef>

#define N_NODES_C 50000
#define N_EDGES_C 1600000

typedef __attribute__((ext_vector_type(8)))  short bf16x8;
typedef __attribute__((ext_vector_type(16))) float f32x16;
typedef unsigned short ushort_t;

// ---- workspace layout ----
// [0,512): 8 expsum slots (64B apart); [512,+12.8M): agg fp32; node_bf; weight images
static const size_t AGG_OFF   = 512;
static const size_t NB_OFF    = 512 + (size_t)N_NODES_C * 64 * 4;          // +12.8MB
static const size_t WIMG_OFF  = NB_OFF + (size_t)N_NODES_C * 64 * 2;       // +6.4MB
static const size_t WUIMG_OFF = WIMG_OFF + 49152;                          // Wm(20480)+Wa(20480)+W2s(8192)

__device__ __forceinline__ float swish_(float v) { return v / (1.0f + __expf(-v)); }

__device__ __forceinline__ unsigned short f2bf(float f) {
    unsigned int u = __float_as_uint(f);
    return (unsigned short)((u + 0x7FFFu + ((u >> 16) & 1u)) >> 16);
}
__device__ __forceinline__ unsigned int pack2(float a, float b) {
    return (unsigned int)f2bf(a) | ((unsigned int)f2bf(b) << 16);
}
__device__ __forceinline__ bf16x8 pack8(float4 a, float4 b) {
    union { uint4 u; bf16x8 v; } un;
    un.u.x = pack2(a.x, a.y); un.u.y = pack2(a.z, a.w);
    un.u.z = pack2(b.x, b.y); un.u.w = pack2(b.z, b.w);
    return un.v;
}

// async global->LDS, 16B per lane (dest: wave-uniform base + lane*16)
typedef __attribute__((address_space(3))) unsigned int lds_u32_t;
typedef const __attribute__((address_space(1))) unsigned int glb_u32_t;
__device__ __forceinline__ void glds16(const void* g, void* l) {
    __builtin_amdgcn_global_load_lds((glb_u32_t*)g, (lds_u32_t*)l, 16, 0, 0);
}

// ---- prep: node features fp32 -> bf16 image ----
__global__ __launch_bounds__(256) void k_prep_node(const float* __restrict__ node,
                                                   ushort_t* __restrict__ node_bf)
{
    int i = blockIdx.x * 256 + threadIdx.x;
    if (i >= N_NODES_C * 64 / 8) return;
    const float4* s = (const float4*)node + (size_t)i * 2;
    float4 a = s[0], b = s[1];
    uint4 p = { pack2(a.x,a.y), pack2(a.z,a.w), pack2(b.x,b.y), pack2(b.z,b.w) };
    ((uint4*)node_bf)[i] = p;
}

// ---- prep: bf16 weight images in exact LDS layouts ----
// wm/wa: [64][160] = W^T rows; w2s: [64][64] chunk-XOR + k-interleaved (k'=2(k&31)+(k>>5));
// wu1t: [64][136] padded; wu2t: [64][72] padded (legacy k_upd layouts)
__global__ __launch_bounds__(256) void k_prep_w(
    const float* __restrict__ W1, const float* __restrict__ Wa1,
    const float* __restrict__ W2, const float* __restrict__ Wu1,
    const float* __restrict__ Wu2,
    ushort_t* __restrict__ wm, ushort_t* __restrict__ wa, ushort_t* __restrict__ w2s,
    ushort_t* __restrict__ wu1t, ushort_t* __restrict__ wu2t)
{
    int b = blockIdx.x, t = threadIdx.x;
    if (b < 20) {                 // wm: 5120 dwords
        int p = b * 256 + t; int n = p / 80, j = p - n * 80;
        ((unsigned int*)wm)[n * 80 + j] = pack2(W1[(size_t)(2*j) * 64 + n], W1[(size_t)(2*j+1) * 64 + n]);
    } else if (b < 40) {          // wa: 5120 dwords
        int p = (b - 20) * 256 + t; int n = p / 80, j = p - n * 80;
        ((unsigned int*)wa)[n * 80 + j] = pack2(Wa1[(size_t)(2*j) * 64 + n], Wa1[(size_t)(2*j+1) * 64 + n]);
    } else if (b < 48) {          // w2s: 2048 dwords
        int p = (b - 40) * 256 + t; int n = p >> 5, q = p & 31, c = q >> 2, j = q & 3;
        ((unsigned int*)w2s)[n * 32 + ((c ^ (n & 7)) << 2) + j] =
            pack2(W2[(size_t)(c*4 + j) * 64 + n], W2[(size_t)(c*4 + j + 32) * 64 + n]);
    } else if (b < 65) {          // wu1t: 4352 dwords
        int p = (b - 48) * 256 + t; int n = p / 68, j = p - n * 68; int k2 = 2 * j;
        unsigned int v = (k2 < 128) ? pack2(Wu1[(size_t)k2 * 64 + n], Wu1[(size_t)(k2+1) * 64 + n]) : 0u;
        ((unsigned int*)wu1t)[n * 68 + j] = v;
    } else {                      // wu2t: 2304 dwords
        int p = (b - 65) * 256 + t; int n = p / 36, j = p - n * 36; int k2 = 2 * j;
        unsigned int v = (k2 < 64) ? pack2(Wu2[(size_t)k2 * 64 + n], Wu2[(size_t)(k2+1) * 64 + n]) : 0u;
        ((unsigned int*)wu2t)[n * 36 + j] = v;
    }
}

// ---- fused edge kernel: 128 edges/block, 256 threads, 80KB LDS (2 blocks/CU) ----
__global__ __launch_bounds__(256, 2) void k_edge(
    const ushort_t* __restrict__ node_bf, const float* __restrict__ edgef,
    const int* __restrict__ senders, const int* __restrict__ receivers,
    const ushort_t* __restrict__ wimg,
    const float* __restrict__ b1, const float* __restrict__ ba1,
    const float* __restrict__ Wa2, const float* __restrict__ ba2,
    const float* __restrict__ b2,
    float* __restrict__ expsum, float* __restrict__ agg)
{
    __shared__ ushort_t SMEM[40960];          // 81920 B exactly
    ushort_t* As  = SMEM;                     // [128][64] sender rows, chunk-swizzled
    ushort_t* Ar  = SMEM + 8192;              // [128][64] receiver rows
    ushort_t* Wm  = SMEM + 16384;             // [64][160]
    ushort_t* Wa  = SMEM + 26624;             // [64][160]; H[128][72] overlays post-barrier
    ushort_t* W2s = SMEM + 36864;             // [64][64] XOR-swizzled, k-interleaved

    const int tid = threadIdx.x;
    const int e0 = blockIdx.x * 128;
    const int lane = tid & 63, w = tid >> 6;
    const int lr = lane & 31, hi = lane >> 5, kh = hi * 8;

    // weights: Wm+Wa contiguous (2560 chunks), W2s (512 chunks)
    for (int c = tid; c < 2560; c += 256)
        glds16((const char*)wimg + c * 16, (char*)Wm + c * 16);
    for (int c = tid; c < 512; c += 256)
        glds16((const char*)wimg + 40960 + c * 16, (char*)W2s + c * 16);
    // gathered A rows: LDS chunk c holds source chunk c^(row&7)
    #pragma unroll
    for (int i = 0; i < 4; ++i) {
        int cg = tid + i * 256;
        int row = cg >> 3, c = cg & 7;
        glds16(node_bf + (size_t)senders[e0 + row] * 64 + ((c ^ (row & 7)) << 3),
               (char*)As + cg * 16);
    }
    #pragma unroll
    for (int i = 0; i < 4; ++i) {
        int cg = tid + i * 256;
        int row = cg >> 3, c = cg & 7;
        glds16(node_bf + (size_t)receivers[e0 + row] * 64 + ((c ^ (row & 7)) << 3),
               (char*)Ar + cg * 16);
    }
    // edge features k=128..159: direct global->reg->bf16 A-fragments
    bf16x8 ae0, ae1;
    {
        const float4* ep = (const float4*)(edgef + (size_t)(e0 + w * 32 + lr) * 32);
        ae0 = pack8(ep[2 * hi], ep[2 * hi + 1]);
        ae1 = pack8(ep[4 + 2 * hi], ep[4 + 2 * hi + 1]);
    }
    __syncthreads();

    // GEMM1: msg_in[128x160] @ {Wm, Wa}
    f32x16 ca0, ca1, cm0, cm1;
    #pragma unroll
    for (int j = 0; j < 16; ++j) { ca0[j]=0.f; ca1[j]=0.f; cm0[j]=0.f; cm1[j]=0.f; }
    const ushort_t* asr = As + (w * 32 + lr) * 64;
    const ushort_t* arr = Ar + (w * 32 + lr) * 64;
    const ushort_t* wm0 = Wm + lr * 160 + kh;
    const ushort_t* wm1 = Wm + (32 + lr) * 160 + kh;
    const ushort_t* wa0 = Wa + lr * 160 + kh;
    const ushort_t* wa1 = Wa + (32 + lr) * 160 + kh;
    #pragma unroll
    for (int kk = 0; kk < 4; ++kk) {
        bf16x8 a = *(const bf16x8*)(asr + (((2*kk + hi) ^ (lr & 7)) << 3));
        cm0 = __builtin_amdgcn_mfma_f32_32x32x16_bf16(a, *(const bf16x8*)(wm0 + kk*16), cm0, 0,0,0);
        cm1 = __builtin_amdgcn_mfma_f32_32x32x16_bf16(a, *(const bf16x8*)(wm1 + kk*16), cm1, 0,0,0);
        ca0 = __builtin_amdgcn_mfma_f32_32x32x16_bf16(a, *(const bf16x8*)(wa0 + kk*16), ca0, 0,0,0);
        ca1 = __builtin_amdgcn_mfma_f32_32x32x16_bf16(a, *(const bf16x8*)(wa1 + kk*16), ca1, 0,0,0);
    }
    #pragma unroll
    for (int kk = 4; kk < 8; ++kk) {
        bf16x8 a = *(const bf16x8*)(arr + (((2*(kk-4) + hi) ^ (lr & 7)) << 3));
        cm0 = __builtin_amdgcn_mfma_f32_32x32x16_bf16(a, *(const bf16x8*)(wm0 + kk*16), cm0, 0,0,0);
        cm1 = __builtin_amdgcn_mfma_f32_32x32x16_bf16(a, *(const bf16x8*)(wm1 + kk*16), cm1, 0,0,0);
        ca0 = __builtin_amdgcn_mfma_f32_32x32x16_bf16(a, *(const bf16x8*)(wa0 + kk*16), ca0, 0,0,0);
        ca1 = __builtin_amdgcn_mfma_f32_32x32x16_bf16(a, *(const bf16x8*)(wa1 + kk*16), ca1, 0,0,0);
    }
    {
        bf16x8 a = ae0;
        cm0 = __builtin_amdgcn_mfma_f32_32x32x16_bf16(a, *(const bf16x8*)(wm0 + 128), cm0, 0,0,0);
        cm1 = __builtin_amdgcn_mfma_f32_32x32x16_bf16(a, *(const bf16x8*)(wm1 + 128), cm1, 0,0,0);
        ca0 = __builtin_amdgcn_mfma_f32_32x32x16_bf16(a, *(const bf16x8*)(wa0 + 128), ca0, 0,0,0);
        ca1 = __builtin_amdgcn_mfma_f32_32x32x16_bf16(a, *(const bf16x8*)(wa1 + 128), ca1, 0,0,0);
        a = ae1;
        cm0 = __builtin_amdgcn_mfma_f32_32x32x16_bf16(a, *(const bf16x8*)(wm0 + 144), cm0, 0,0,0);
        cm1 = __builtin_amdgcn_mfma_f32_32x32x16_bf16(a, *(const bf16x8*)(wm1 + 144), cm1, 0,0,0);
        ca0 = __builtin_amdgcn_mfma_f32_32x32x16_bf16(a, *(const bf16x8*)(wa0 + 144), ca0, 0,0,0);
        ca1 = __builtin_amdgcn_mfma_f32_32x32x16_bf16(a, *(const bf16x8*)(wa1 + 144), ca1, 0,0,0);
    }
    __syncthreads();   // As/Ar/Wa become scratch below

    // H_att = bf16(swish(ca+ba1)*Wa2), k-interleaved cols (k'=2(k&31)+(k>>5))
    ushort_t* H = Wa;                          // [128][72]
    const float bb0 = ba1[lr], bb1 = ba1[32 + lr];
    const float wv0 = Wa2[lr], wv1 = Wa2[32 + lr];
    #pragma unroll
    for (int t = 0; t < 16; ++t) {
        int r = (t & 3) + 8 * (t >> 2) + 4 * hi;
        *(unsigned int*)(H + (w * 32 + r) * 72 + 2 * lr) =
            pack2(swish_(ca0[t] + bb0) * wv0, swish_(ca1[t] + bb1) * wv1);
    }
    // GEMM2a: logits = H_att @ ones  (D[r][c] = logit[r] for every c)
    f32x16 da;
    #pragma unroll
    for (int j = 0; j < 16; ++j) da[j] = 0.f;
    bf16x8 ones;
    #pragma unroll
    for (int i = 0; i < 8; ++i) ones[i] = (short)0x3F80;   // bf16 1.0
    const ushort_t* hp = H + (w * 32 + lr) * 72 + kh;
    #pragma unroll
    for (int kk = 0; kk < 4; ++kk)
        da = __builtin_amdgcn_mfma_f32_32x32x16_bf16(*(const bf16x8*)(hp + kk*16), ones, da, 0,0,0);

    // p[t] = exp(logit) per C-row, register-local; wave expsum via global atomic
    const float ba2v = ba2[0];
    float p[16];
    float ps = 0.f;
    #pragma unroll
    for (int t = 0; t < 16; ++t) { p[t] = __expf(da[t] + ba2v); ps += p[t]; }
    ps += __shfl_xor(ps, 1);  ps += __shfl_xor(ps, 2);  ps += __shfl_xor(ps, 4);
    ps += __shfl_xor(ps, 8);  ps += __shfl_xor(ps, 16); ps += __shfl_xor(ps, 32);
    if (lane == 0) atomicAdd(&expsum[w * 16], ps * 0.03125f);   // /32 (each row counted 32x)

    // H_msg = bf16(swish(cm+b1)), same region (wave-private rows, in-order DS)
    const float b10 = b1[lr], b11 = b1[32 + lr];
    #pragma unroll
    for (int t = 0; t < 16; ++t) {
        int r = (t & 3) + 8 * (t >> 2) + 4 * hi;
        *(unsigned int*)(H + (w * 32 + r) * 72 + 2 * lr) =
            pack2(swish_(cm0[t] + b10), swish_(cm1[t] + b11));
    }
    // GEMM2: msg = H @ W2 (k-interleaved both sides)
    f32x16 d0, d1;
    #pragma unroll
    for (int j = 0; j < 16; ++j) { d0[j] = 0.f; d1[j] = 0.f; }
    const ushort_t* q0 = W2s + lr * 64;
    const ushort_t* q1 = W2s + (32 + lr) * 64;
    #pragma unroll
    for (int kk = 0; kk < 4; ++kk) {
        bf16x8 a = *(const bf16x8*)(hp + kk * 16);
        int sw = ((2*kk + hi) ^ (lr & 7)) << 3;
        d0 = __builtin_amdgcn_mfma_f32_32x32x16_bf16(a, *(const bf16x8*)(q0 + sw), d0, 0,0,0);
        d1 = __builtin_amdgcn_mfma_f32_32x32x16_bf16(a, *(const bf16x8*)(q1 + sw), d1, 0,0,0);
    }

    // m = (d + b2) * p -> LDS transpose (As+Ar region, fp32 [128][64] interleaved cols)
    float* Msc = (float*)SMEM;
    const float b20 = b2[lr], b21 = b2[32 + lr];
    #pragma unroll
    for (int t = 0; t < 16; ++t) {
        int r = (t & 3) + 8 * (t >> 2) + 4 * hi;
        float2 mv = { (d0[t] + b20) * p[t], (d1[t] + b21) * p[t] };
        *(float2*)(Msc + (w * 32 + r) * 64 + 2 * lr) = mv;
    }
    // segmented scatter: lane = unit, rows in order; receivers sorted -> run accumulate
    const int cj = (lane < 32) ? 2 * lane : 2 * (lane - 32) + 1;
    const int ews = e0 + w * 32;
    float acc = 0.f;
    int cur = receivers[ews];
    #pragma unroll 4
    for (int i = 0; i < 32; ++i) {
        int rr = receivers[ews + i];
        if (rr != cur) {
            atomicAdd(&agg[(size_t)cur * 64 + lane], acc);
            acc = 0.f; cur = rr;
        }
        acc += Msc[(w * 32 + i) * 64 + cj];
    }
    atomicAdd(&agg[(size_t)cur * 64 + lane], acc);
}

// ---- update MLP (MFMA), 128 nodes/block ----
__global__ __launch_bounds__(256) void k_upd(
    const ushort_t* __restrict__ node_bf, const float* __restrict__ agg,
    const ushort_t* __restrict__ wuimg,
    const float* __restrict__ bu1, const float* __restrict__ bu2,
    const float* __restrict__ expsum, float* __restrict__ out)
{
    __shared__ ushort_t Un[128 * 64];
    __shared__ ushort_t Ua[128 * 64];
    __shared__ ushort_t Wu[13312];        // Wu1t[64][136] @0, Wu2t[64][72] @8704 (shorts)
    __shared__ ushort_t H2[128 * 72];

    const int tid = threadIdx.x;
    const int n0 = blockIdx.x * 128;

    for (int c = tid; c < 1664; c += 256)
        glds16((const char*)wuimg + c * 16, (char*)Wu + c * 16);
    #pragma unroll
    for (int i = 0; i < 4; ++i) {
        int cg = tid + i * 256;
        int row = cg >> 3, c = cg & 7;
        int n = n0 + row; if (n >= N_NODES_C) n = N_NODES_C - 1;
        glds16(node_bf + (size_t)n * 64 + ((c ^ (row & 7)) << 3), (char*)Un + cg * 16);
    }
    float z = 0.f;
    #pragma unroll
    for (int q = 0; q < 8; ++q) z += expsum[q * 16];
    const float invZ = 1.0f / z;
    {
        int row = tid >> 1, hf = tid & 1;
        int n = n0 + row; if (n >= N_NODES_C) n = N_NODES_C - 1;
        const float4* ap = (const float4*)(agg + (size_t)n * 64 + hf * 32);
        int r7 = row & 7;
        #pragma unroll
        for (int q = 0; q < 4; ++q) {
            float4 x = ap[2 * q], y = ap[2 * q + 1];
            uint4 pk = { pack2(x.x * invZ, x.y * invZ), pack2(x.z * invZ, x.w * invZ),
                         pack2(y.x * invZ, y.y * invZ), pack2(y.z * invZ, y.w * invZ) };
            int chunk = hf * 4 + q;
            *(uint4*)(Ua + row * 64 + ((chunk ^ r7) << 3)) = pk;
        }
    }
    __syncthreads();

    const int lane = tid & 63, w = tid >> 6;
    const int lr = lane & 31, hi = lane >> 5, kh = hi * 8;
    const int row_a = w * 32 + lr, r7 = lr & 7;

    f32x16 c0, c1;
    #pragma unroll
    for (int j = 0; j < 16; ++j) { c0[j] = 0.f; c1[j] = 0.f; }
    const ushort_t* un = Un + row_a * 64;
    const ushort_t* ua = Ua + row_a * 64;
    const ushort_t* w10 = Wu + lr * 136 + kh;
    const ushort_t* w11 = Wu + (32 + lr) * 136 + kh;
    #pragma unroll
    for (int kk = 0; kk < 4; ++kk) {
        bf16x8 a = *(const bf16x8*)(un + (((2*kk + hi) ^ r7) << 3));
        c0 = __builtin_amdgcn_mfma_f32_32x32x16_bf16(a, *(const bf16x8*)(w10 + kk*16), c0, 0,0,0);
        c1 = __builtin_amdgcn_mfma_f32_32x32x16_bf16(a, *(const bf16x8*)(w11 + kk*16), c1, 0,0,0);
    }
    #pragma unroll
    for (int kk = 4; kk < 8; ++kk) {
        bf16x8 a = *(const bf16x8*)(ua + (((2*(kk-4) + hi) ^ r7) << 3));
        c0 = __builtin_amdgcn_mfma_f32_32x32x16_bf16(a, *(const bf16x8*)(w10 + kk*16), c0, 0,0,0);
        c1 = __builtin_amdgcn_mfma_f32_32x32x16_bf16(a, *(const bf16x8*)(w11 + kk*16), c1, 0,0,0);
    }
    const float bb0 = bu1[lr], bb1 = bu1[32 + lr];
    #pragma unroll
    for (int t = 0; t < 16; ++t) {
        int r = (t & 3) + 8 * (t >> 2) + 4 * hi;
        int g = (w * 32 + r) * 72;
        H2[g + lr]      = f2bf(swish_(c0[t] + bb0));
        H2[g + 32 + lr] = f2bf(swish_(c1[t] + bb1));
    }
    f32x16 d0, d1;
    #pragma unroll
    for (int j = 0; j < 16; ++j) { d0[j] = 0.f; d1[j] = 0.f; }
    const ushort_t* hp = H2 + row_a * 72 + kh;
    const ushort_t* w20 = Wu + 8704 + lr * 72 + kh;
    const ushort_t* w21 = Wu + 8704 + (32 + lr) * 72 + kh;
    #pragma unroll
    for (int kk = 0; kk < 4; ++kk) {
        bf16x8 a = *(const bf16x8*)(hp + kk * 16);
        d0 = __builtin_amdgcn_mfma_f32_32x32x16_bf16(a, *(const bf16x8*)(w20 + kk*16), d0, 0,0,0);
        d1 = __builtin_amdgcn_mfma_f32_32x32x16_bf16(a, *(const bf16x8*)(w21 + kk*16), d1, 0,0,0);
    }
    const float ob0 = bu2[lr], ob1 = bu2[32 + lr];
    #pragma unroll
    for (int t = 0; t < 16; ++t) {
        int r = (t & 3) + 8 * (t >> 2) + 4 * hi;
        int g = n0 + w * 32 + r;
        if (g < N_NODES_C) {
            out[(size_t)g * 64 + lr]      = d0[t] + ob0;
            out[(size_t)g * 64 + 32 + lr] = d1[t] + ob1;
        }
    }
}

extern "C" void kernel_launch(void* const* d_in, const int* in_sizes, int n_in,
                              void* d_out, int out_size, void* d_ws, size_t ws_size,
                              hipStream_t stream)
{
    const float* node      = (const float*)d_in[0];
    const float* edgef     = (const float*)d_in[1];
    const int*   senders   = (const int*)d_in[2];
    const int*   receivers = (const int*)d_in[3];
    const float* W1  = (const float*)d_in[4];
    const float* b1  = (const float*)d_in[5];
    const float* W2  = (const float*)d_in[6];
    const float* b2  = (const float*)d_in[7];
    const float* Wa1 = (const float*)d_in[8];
    const float* ba1 = (const float*)d_in[9];
    const float* Wa2 = (const float*)d_in[10];
    const float* ba2 = (const float*)d_in[11];
    const float* Wu1 = (const float*)d_in[12];
    const float* bu1 = (const float*)d_in[13];
    const float* Wu2 = (const float*)d_in[14];
    const float* bu2 = (const float*)d_in[15];
    float* out = (float*)d_out;

    char* ws = (char*)d_ws;
    float*    expsum  = (float*)ws;
    float*    agg     = (float*)(ws + AGG_OFF);
    ushort_t* node_bf = (ushort_t*)(ws + NB_OFF);
    ushort_t* wimg    = (ushort_t*)(ws + WIMG_OFF);
    ushort_t* wuimg   = (ushort_t*)(ws + WUIMG_OFF);

    ushort_t* wm   = wimg;                 // 20480 B
    ushort_t* wa   = wimg + 10240;         // +20480 B
    ushort_t* w2s  = wimg + 20480;         // +8192 B
    ushort_t* wu1t = wuimg;                // 17408 B
    ushort_t* wu2t = wuimg + 8704;         // +9216 B

    hipMemsetAsync(ws, 0, AGG_OFF + (size_t)N_NODES_C * 64 * 4, stream);

    k_prep_node<<<(N_NODES_C * 64 / 8 + 255) / 256, 256, 0, stream>>>(node, node_bf);
    k_prep_w<<<74, 256, 0, stream>>>(W1, Wa1, W2, Wu1, Wu2, wm, wa, w2s, wu1t, wu2t);
    k_edge<<<N_EDGES_C / 128, 256, 0, stream>>>(node_bf, edgef, senders, receivers,
                                                wimg, b1, ba1, Wa2, ba2, b2, expsum, agg);
    k_upd<<<(N_NODES_C + 127) / 128, 256, 0, stream>>>(node_bf, agg, wuimg,
                                                       bu1, bu2, expsum, out);
}

// Round 5
// 506.421 us; speedup vs baseline: 1.2461x; 1.2461x over previous
//
#include <hip/hip_runtime.h>
#include <cstdint>
#include <cstddef>

#define N_NODES_C 50000
#define N_EDGES_C 1600000
#define N_WTILES  50000          // 32-edge wave-tiles
#define N_BLOCKS  512            // 2 blocks/CU, persistent
#define N_GWAVES  (N_BLOCKS * 4)

typedef __attribute__((ext_vector_type(8)))  short bf16x8;
typedef __attribute__((ext_vector_type(16))) float f32x16;
typedef unsigned short ushort_t;

// ---- workspace layout ----
// [0,512): 8 expsum slots (64B apart); [512,+12.8M): agg fp32; node_bf; weight images
static const size_t AGG_OFF   = 512;
static const size_t NB_OFF    = 512 + (size_t)N_NODES_C * 64 * 4;
static const size_t WIMG_OFF  = NB_OFF + (size_t)N_NODES_C * 64 * 2;
static const size_t WUIMG_OFF = WIMG_OFF + 51200;   // wm(21504)+wa(21504)+w2s(8192)

__device__ __forceinline__ float swish_(float v) { return v / (1.0f + __expf(-v)); }

__device__ __forceinline__ unsigned short f2bf(float f) {
    unsigned int u = __float_as_uint(f);
    return (unsigned short)((u + 0x7FFFu + ((u >> 16) & 1u)) >> 16);
}
__device__ __forceinline__ unsigned int pack2(float a, float b) {
    return (unsigned int)f2bf(a) | ((unsigned int)f2bf(b) << 16);
}
__device__ __forceinline__ bf16x8 pack8(float4 a, float4 b) {
    union { uint4 u; bf16x8 v; } un;
    un.u.x = pack2(a.x, a.y); un.u.y = pack2(a.z, a.w);
    un.u.z = pack2(b.x, b.y); un.u.w = pack2(b.z, b.w);
    return un.v;
}
__device__ __forceinline__ bf16x8 as_bf8(uint4 u) {
    union { uint4 u; bf16x8 v; } un; un.u = u; return un.v;
}

// async global->LDS, 16B per lane
typedef __attribute__((address_space(3))) unsigned int lds_u32_t;
typedef const __attribute__((address_space(1))) unsigned int glb_u32_t;
__device__ __forceinline__ void glds16(const void* g, void* l) {
    __builtin_amdgcn_global_load_lds((glb_u32_t*)g, (lds_u32_t*)l, 16, 0, 0);
}

// ---- prep: node fp32->bf16, zero agg + expsum ----
__global__ __launch_bounds__(256) void k_prep_node(const float* __restrict__ node,
                                                   ushort_t* __restrict__ node_bf,
                                                   float* __restrict__ ws_base)
{
    int i = blockIdx.x * 256 + threadIdx.x;
    if (blockIdx.x == 0 && threadIdx.x < 128) ws_base[threadIdx.x] = 0.0f;
    if (i >= N_NODES_C * 64 / 8) return;
    const float4* s = (const float4*)node + (size_t)i * 2;
    float4 a = s[0], b = s[1];
    uint4 p = { pack2(a.x,a.y), pack2(a.z,a.w), pack2(b.x,b.y), pack2(b.z,b.w) };
    ((uint4*)node_bf)[i] = p;
    float4 z = {0.f, 0.f, 0.f, 0.f};
    float* agg = ws_base + 128;           // AGG_OFF = 512 bytes
    ((float4*)agg)[i * 2]     = z;        // zero 8 agg floats / thread
    ((float4*)agg)[i * 2 + 1] = z;
}

// ---- prep: bf16 weight images in exact LDS layouts ----
__global__ __launch_bounds__(256) void k_prep_w(
    const float* __restrict__ W1, const float* __restrict__ Wa1,
    const float* __restrict__ W2, const float* __restrict__ Wu1,
    const float* __restrict__ Wu2,
    ushort_t* __restrict__ wm, ushort_t* __restrict__ wa, ushort_t* __restrict__ w2s,
    ushort_t* __restrict__ wu1t, ushort_t* __restrict__ wu2t)
{
    int b = blockIdx.x, t = threadIdx.x;
    if (b < 21) {                          // wm: [64][84] dwords, padded
        int p = b * 256 + t; if (p >= 5376) return;
        int n = p / 84, j = p - n * 84;
        unsigned int v = (j < 80) ? pack2(W1[(size_t)(2*j)*64 + n], W1[(size_t)(2*j+1)*64 + n]) : 0u;
        ((unsigned int*)wm)[p] = v;
    } else if (b < 42) {                   // wa
        int p = (b - 21) * 256 + t; if (p >= 5376) return;
        int n = p / 84, j = p - n * 84;
        unsigned int v = (j < 80) ? pack2(Wa1[(size_t)(2*j)*64 + n], Wa1[(size_t)(2*j+1)*64 + n]) : 0u;
        ((unsigned int*)wa)[p] = v;
    } else if (b < 50) {                   // w2s: [64][32] dwords, XOR chunks, k-interleaved
        int p = (b - 42) * 256 + t;
        int n = p >> 5, q = p & 31, c = q >> 2, jj = q & 3;
        ((unsigned int*)w2s)[n * 32 + ((c ^ (n & 7)) << 2) + jj] =
            pack2(W2[(size_t)(c*4 + jj) * 64 + n], W2[(size_t)(c*4 + jj + 32) * 64 + n]);
    } else if (b < 67) {                   // wu1t: [64][68] dwords
        int p = (b - 50) * 256 + t; if (p >= 4352) return;
        int n = p / 68, j = p - n * 68;
        unsigned int v = (2*j < 128) ? pack2(Wu1[(size_t)(2*j)*64 + n], Wu1[(size_t)(2*j+1)*64 + n]) : 0u;
        ((unsigned int*)wu1t)[p] = v;
    } else {                               // wu2t: [64][36] dwords
        int p = (b - 67) * 256 + t; if (p >= 2304) return;
        int n = p / 36, j = p - n * 36;
        unsigned int v = (2*j < 64) ? pack2(Wu2[(size_t)(2*j)*64 + n], Wu2[(size_t)(2*j+1)*64 + n]) : 0u;
        ((unsigned int*)wu2t)[p] = v;
    }
}

// per-tile register buffer (all indices compile-time after unroll)
struct EBuf { uint4 sn[4]; uint4 rn[4]; float4 ef[4]; };

__device__ __forceinline__ void issue_data(EBuf& b, const ushort_t* node_bf,
                                           const float* edgef, int s, int r,
                                           long e, int hi)
{
    const uint4* sp = (const uint4*)(node_bf + (size_t)s * 64);
    const uint4* rp = (const uint4*)(node_bf + (size_t)r * 64);
    #pragma unroll
    for (int kk = 0; kk < 4; ++kk) b.sn[kk] = sp[2 * kk + hi];
    #pragma unroll
    for (int kk = 0; kk < 4; ++kk) b.rn[kk] = rp[2 * kk + hi];
    const float4* ep = (const float4*)(edgef + (size_t)e * 32);
    b.ef[0] = ep[2 * hi];     b.ef[1] = ep[2 * hi + 1];
    b.ef[2] = ep[4 + 2 * hi]; b.ef[3] = ep[5 + 2 * hi];
}

// ---- persistent fused edge kernel: no per-tile barriers ----
__global__ __launch_bounds__(256, 2) void k_edge(
    const ushort_t* __restrict__ node_bf, const float* __restrict__ edgef,
    const int* __restrict__ senders, const int* __restrict__ receivers,
    const ushort_t* __restrict__ wimg,
    const float* __restrict__ b1, const float* __restrict__ ba1,
    const float* __restrict__ Wa2, const float* __restrict__ ba2,
    const float* __restrict__ b2,
    float* __restrict__ expsum, float* __restrict__ agg)
{
    __shared__ ushort_t SMEM[34816];            // 69632 B -> 2 blocks/CU
    ushort_t* Wm  = SMEM;                       // [64][168]
    ushort_t* Wa  = SMEM + 10752;               // [64][168]
    ushort_t* W2s = SMEM + 21504;               // [64][64] XOR, k-interleaved
    ushort_t* H   = SMEM + 25600;               // [128][72] bf16 (H / Msc overlay)

    const int tid = threadIdx.x;
    const int lane = tid & 63, w = tid >> 6;
    const int lr = lane & 31, hi = lane >> 5, kh = hi * 8;

    // stage all weights once (51200 B linear)
    for (int c = tid; c < 3200; c += 256)
        glds16((const char*)wimg + c * 16, (char*)SMEM + c * 16);
    __syncthreads();                            // the only barrier

    // wave-tile range (contiguous for sorted-receiver run locality)
    const int g = blockIdx.x * 4 + w;
    const int t0 = (int)(((long)g * N_WTILES) / N_GWAVES);
    const int t1 = (int)(((long)(g + 1) * N_WTILES) / N_GWAVES);

    // B pointers (tile-invariant)
    const ushort_t* wm0 = Wm + lr * 168 + kh;
    const ushort_t* wm1 = Wm + (32 + lr) * 168 + kh;
    const ushort_t* wa0 = Wa + lr * 168 + kh;
    const ushort_t* wa1 = Wa + (32 + lr) * 168 + kh;
    const ushort_t* q0  = W2s + lr * 64;
    const ushort_t* q1  = W2s + (32 + lr) * 64;
    ushort_t* Hw = H + (w * 32) * 72;
    const ushort_t* hp = H + (w * 32 + lr) * 72 + kh;

    const float bb0 = ba1[lr], bb1 = ba1[32 + lr];
    const float wv0 = Wa2[lr], wv1 = Wa2[32 + lr];
    const float ba2v = ba2[0];
    const float b10 = b1[lr], b11 = b1[32 + lr];
    const float b20 = b2[lr], b21 = b2[32 + lr];

    bf16x8 ones;
    #pragma unroll
    for (int i = 0; i < 8; ++i) ones[i] = (short)0x3F80;

    // pipeline prologue
    EBuf buf;
    int s_c = senders[(size_t)t0 * 32 + lr];
    int r_c = receivers[(size_t)t0 * 32 + lr];
    issue_data(buf, node_bf, edgef, s_c, r_c, (long)t0 * 32 + lr, hi);

    float zacc = 0.0f;

    for (int t = t0; t < t1; ++t) {
        const bool more = (t + 1 < t1);
        int s2 = 0, r2 = 0;
        if (more) {
            s2 = senders[(size_t)(t + 1) * 32 + lr];
            r2 = receivers[(size_t)(t + 1) * 32 + lr];
        }

        // GEMM1: 32 edges x 160 @ {Wm, Wa}
        f32x16 ca0, ca1, cm0, cm1;
        #pragma unroll
        for (int j = 0; j < 16; ++j) { ca0[j]=0.f; ca1[j]=0.f; cm0[j]=0.f; cm1[j]=0.f; }
        #pragma unroll
        for (int kk = 0; kk < 4; ++kk) {
            bf16x8 a = as_bf8(buf.sn[kk]);
            cm0 = __builtin_amdgcn_mfma_f32_32x32x16_bf16(a, *(const bf16x8*)(wm0 + kk*16), cm0, 0,0,0);
            cm1 = __builtin_amdgcn_mfma_f32_32x32x16_bf16(a, *(const bf16x8*)(wm1 + kk*16), cm1, 0,0,0);
            ca0 = __builtin_amdgcn_mfma_f32_32x32x16_bf16(a, *(const bf16x8*)(wa0 + kk*16), ca0, 0,0,0);
            ca1 = __builtin_amdgcn_mfma_f32_32x32x16_bf16(a, *(const bf16x8*)(wa1 + kk*16), ca1, 0,0,0);
        }
        #pragma unroll
        for (int kk = 4; kk < 8; ++kk) {
            bf16x8 a = as_bf8(buf.rn[kk - 4]);
            cm0 = __builtin_amdgcn_mfma_f32_32x32x16_bf16(a, *(const bf16x8*)(wm0 + kk*16), cm0, 0,0,0);
            cm1 = __builtin_amdgcn_mfma_f32_32x32x16_bf16(a, *(const bf16x8*)(wm1 + kk*16), cm1, 0,0,0);
            ca0 = __builtin_amdgcn_mfma_f32_32x32x16_bf16(a, *(const bf16x8*)(wa0 + kk*16), ca0, 0,0,0);
            ca1 = __builtin_amdgcn_mfma_f32_32x32x16_bf16(a, *(const bf16x8*)(wa1 + kk*16), ca1, 0,0,0);
        }
        {
            bf16x8 a = pack8(buf.ef[0], buf.ef[1]);
            cm0 = __builtin_amdgcn_mfma_f32_32x32x16_bf16(a, *(const bf16x8*)(wm0 + 128), cm0, 0,0,0);
            cm1 = __builtin_amdgcn_mfma_f32_32x32x16_bf16(a, *(const bf16x8*)(wm1 + 128), cm1, 0,0,0);
            ca0 = __builtin_amdgcn_mfma_f32_32x32x16_bf16(a, *(const bf16x8*)(wa0 + 128), ca0, 0,0,0);
            ca1 = __builtin_amdgcn_mfma_f32_32x32x16_bf16(a, *(const bf16x8*)(wa1 + 128), ca1, 0,0,0);
            a = pack8(buf.ef[2], buf.ef[3]);
            cm0 = __builtin_amdgcn_mfma_f32_32x32x16_bf16(a, *(const bf16x8*)(wm0 + 144), cm0, 0,0,0);
            cm1 = __builtin_amdgcn_mfma_f32_32x32x16_bf16(a, *(const bf16x8*)(wm1 + 144), cm1, 0,0,0);
            ca0 = __builtin_amdgcn_mfma_f32_32x32x16_bf16(a, *(const bf16x8*)(wa0 + 144), ca0, 0,0,0);
            ca1 = __builtin_amdgcn_mfma_f32_32x32x16_bf16(a, *(const bf16x8*)(wa1 + 144), ca1, 0,0,0);
        }

        const int rv = r_c;
        // prefetch next tile's data (latency hidden under epilogue)
        if (more) issue_data(buf, node_bf, edgef, s2, r2, (long)(t + 1) * 32 + lr, hi);
        s_c = s2; r_c = r2;

        // H_att = bf16(swish(ca+ba1)*Wa2), k-interleaved pairs
        #pragma unroll
        for (int tt = 0; tt < 16; ++tt) {
            int r = (tt & 3) + 8 * (tt >> 2) + 4 * hi;
            *(unsigned int*)(Hw + r * 72 + 2 * lr) =
                pack2(swish_(ca0[tt] + bb0) * wv0, swish_(ca1[tt] + bb1) * wv1);
        }
        // logits via ones-GEMM: da[tt] = logit of row r(tt,hi)
        f32x16 da;
        #pragma unroll
        for (int j = 0; j < 16; ++j) da[j] = 0.f;
        #pragma unroll
        for (int kk = 0; kk < 4; ++kk)
            da = __builtin_amdgcn_mfma_f32_32x32x16_bf16(*(const bf16x8*)(hp + kk*16), ones, da, 0,0,0);

        float p[16];
        float ps = 0.f;
        #pragma unroll
        for (int tt = 0; tt < 16; ++tt) { p[tt] = __expf(da[tt] + ba2v); ps += p[tt]; }
        ps += __shfl_xor(ps, 1);  ps += __shfl_xor(ps, 2);  ps += __shfl_xor(ps, 4);
        ps += __shfl_xor(ps, 8);  ps += __shfl_xor(ps, 16); ps += __shfl_xor(ps, 32);
        if (lane == 0) zacc += ps * 0.03125f;

        // H_msg overwrite (same region, wave-private, in-order DS)
        #pragma unroll
        for (int tt = 0; tt < 16; ++tt) {
            int r = (tt & 3) + 8 * (tt >> 2) + 4 * hi;
            *(unsigned int*)(Hw + r * 72 + 2 * lr) =
                pack2(swish_(cm0[tt] + b10), swish_(cm1[tt] + b11));
        }
        // GEMM2: msg = H @ W2
        f32x16 d0, d1;
        #pragma unroll
        for (int j = 0; j < 16; ++j) { d0[j] = 0.f; d1[j] = 0.f; }
        #pragma unroll
        for (int kk = 0; kk < 4; ++kk) {
            bf16x8 a = *(const bf16x8*)(hp + kk * 16);
            int sw = ((2*kk + hi) ^ (lr & 7)) << 3;
            d0 = __builtin_amdgcn_mfma_f32_32x32x16_bf16(a, *(const bf16x8*)(q0 + sw), d0, 0,0,0);
            d1 = __builtin_amdgcn_mfma_f32_32x32x16_bf16(a, *(const bf16x8*)(q1 + sw), d1, 0,0,0);
        }

        // Msc (bf16) into H region: dword lr holds (col lr, col lr+32) of row r
        #pragma unroll
        for (int tt = 0; tt < 16; ++tt) {
            int r = (tt & 3) + 8 * (tt >> 2) + 4 * hi;
            *(unsigned int*)(Hw + r * 72 + 2 * lr) =
                pack2((d0[tt] + b20) * p[tt], (d1[tt] + b21) * p[tt]);
        }

        // segmented scatter: lane = unit col j; receivers sorted -> run accumulate
        const int j = lane;
        const int moff = 2 * (j & 31) + (j >> 5);
        float acc = 0.f;
        int cur = __shfl(rv, 0);
        #pragma unroll 4
        for (int i = 0; i < 32; ++i) {
            int rr = __shfl(rv, i);
            if (rr != cur) {
                atomicAdd(&agg[(size_t)cur * 64 + j], acc);
                acc = 0.f; cur = rr;
            }
            unsigned short mv = Hw[i * 72 + moff];
            acc += __uint_as_float((unsigned int)mv << 16);
        }
        atomicAdd(&agg[(size_t)cur * 64 + j], acc);
    }

    if (lane == 0) atomicAdd(&expsum[(g & 7) * 16], zacc);
}

// ---- update MLP (MFMA), 128 nodes/block ----
__global__ __launch_bounds__(256) void k_upd(
    const ushort_t* __restrict__ node_bf, const float* __restrict__ agg,
    const ushort_t* __restrict__ wuimg,
    const float* __restrict__ bu1, const float* __restrict__ bu2,
    const float* __restrict__ expsum, float* __restrict__ out)
{
    __shared__ ushort_t Un[128 * 64];
    __shared__ ushort_t Ua[128 * 64];
    __shared__ ushort_t Wu[13312];
    __shared__ ushort_t H2[128 * 72];

    const int tid = threadIdx.x;
    const int n0 = blockIdx.x * 128;

    for (int c = tid; c < 1664; c += 256)
        glds16((const char*)wuimg + c * 16, (char*)Wu + c * 16);
    #pragma unroll
    for (int i = 0; i < 4; ++i) {
        int cg = tid + i * 256;
        int row = cg >> 3, c = cg & 7;
        int n = n0 + row; if (n >= N_NODES_C) n = N_NODES_C - 1;
        glds16(node_bf + (size_t)n * 64 + ((c ^ (row & 7)) << 3), (char*)Un + cg * 16);
    }
    float z = 0.f;
    #pragma unroll
    for (int q = 0; q < 8; ++q) z += expsum[q * 16];
    const float invZ = 1.0f / z;
    {
        int row = tid >> 1, hf = tid & 1;
        int n = n0 + row; if (n >= N_NODES_C) n = N_NODES_C - 1;
        const float4* ap = (const float4*)(agg + (size_t)n * 64 + hf * 32);
        int r7 = row & 7;
        #pragma unroll
        for (int q = 0; q < 4; ++q) {
            float4 x = ap[2 * q], y = ap[2 * q + 1];
            uint4 pk = { pack2(x.x * invZ, x.y * invZ), pack2(x.z * invZ, x.w * invZ),
                         pack2(y.x * invZ, y.y * invZ), pack2(y.z * invZ, y.w * invZ) };
            int chunk = hf * 4 + q;
            *(uint4*)(Ua + row * 64 + ((chunk ^ r7) << 3)) = pk;
        }
    }
    __syncthreads();

    const int lane = tid & 63, w = tid >> 6;
    const int lr = lane & 31, hi = lane >> 5, kh = hi * 8;
    const int row_a = w * 32 + lr, r7 = lr & 7;

    f32x16 c0, c1;
    #pragma unroll
    for (int j = 0; j < 16; ++j) { c0[j] = 0.f; c1[j] = 0.f; }
    const ushort_t* un = Un + row_a * 64;
    const ushort_t* ua = Ua + row_a * 64;
    const ushort_t* w10 = Wu + lr * 136 + kh;
    const ushort_t* w11 = Wu + (32 + lr) * 136 + kh;
    #pragma unroll
    for (int kk = 0; kk < 4; ++kk) {
        bf16x8 a = *(const bf16x8*)(un + (((2*kk + hi) ^ r7) << 3));
        c0 = __builtin_amdgcn_mfma_f32_32x32x16_bf16(a, *(const bf16x8*)(w10 + kk*16), c0, 0,0,0);
        c1 = __builtin_amdgcn_mfma_f32_32x32x16_bf16(a, *(const bf16x8*)(w11 + kk*16), c1, 0,0,0);
    }
    #pragma unroll
    for (int kk = 4; kk < 8; ++kk) {
        bf16x8 a = *(const bf16x8*)(ua + (((2*(kk-4) + hi) ^ r7) << 3));
        c0 = __builtin_amdgcn_mfma_f32_32x32x16_bf16(a, *(const bf16x8*)(w10 + kk*16), c0, 0,0,0);
        c1 = __builtin_amdgcn_mfma_f32_32x32x16_bf16(a, *(const bf16x8*)(w11 + kk*16), c1, 0,0,0);
    }
    const float bb0 = bu1[lr], bb1 = bu1[32 + lr];
    #pragma unroll
    for (int t = 0; t < 16; ++t) {
        int r = (t & 3) + 8 * (t >> 2) + 4 * hi;
        int gg = (w * 32 + r) * 72;
        H2[gg + lr]      = f2bf(swish_(c0[t] + bb0));
        H2[gg + 32 + lr] = f2bf(swish_(c1[t] + bb1));
    }
    f32x16 d0, d1;
    #pragma unroll
    for (int j = 0; j < 16; ++j) { d0[j] = 0.f; d1[j] = 0.f; }
    const ushort_t* hp = H2 + row_a * 72 + kh;
    const ushort_t* w20 = Wu + 8704 + lr * 72 + kh;
    const ushort_t* w21 = Wu + 8704 + (32 + lr) * 72 + kh;
    #pragma unroll
    for (int kk = 0; kk < 4; ++kk) {
        bf16x8 a = *(const bf16x8*)(hp + kk * 16);
        d0 = __builtin_amdgcn_mfma_f32_32x32x16_bf16(a, *(const bf16x8*)(w20 + kk*16), d0, 0,0,0);
        d1 = __builtin_amdgcn_mfma_f32_32x32x16_bf16(a, *(const bf16x8*)(w21 + kk*16), d1, 0,0,0);
    }
    const float ob0 = bu2[lr], ob1 = bu2[32 + lr];
    #pragma unroll
    for (int t = 0; t < 16; ++t) {
        int r = (t & 3) + 8 * (t >> 2) + 4 * hi;
        int gg = n0 + w * 32 + r;
        if (gg < N_NODES_C) {
            out[(size_t)gg * 64 + lr]      = d0[t] + ob0;
            out[(size_t)gg * 64 + 32 + lr] = d1[t] + ob1;
        }
    }
}

extern "C" void kernel_launch(void* const* d_in, const int* in_sizes, int n_in,
                              void* d_out, int out_size, void* d_ws, size_t ws_size,
                              hipStream_t stream)
{
    const float* node      = (const float*)d_in[0];
    const float* edgef     = (const float*)d_in[1];
    const int*   senders   = (const int*)d_in[2];
    const int*   receivers = (const int*)d_in[3];
    const float* W1  = (const float*)d_in[4];
    const float* b1  = (const float*)d_in[5];
    const float* W2  = (const float*)d_in[6];
    const float* b2  = (const float*)d_in[7];
    const float* Wa1 = (const float*)d_in[8];
    const float* ba1 = (const float*)d_in[9];
    const float* Wa2 = (const float*)d_in[10];
    const float* ba2 = (const float*)d_in[11];
    const float* Wu1 = (const float*)d_in[12];
    const float* bu1 = (const float*)d_in[13];
    const float* Wu2 = (const float*)d_in[14];
    const float* bu2 = (const float*)d_in[15];
    float* out = (float*)d_out;

    char* ws = (char*)d_ws;
    float*    expsum  = (float*)ws;
    float*    agg     = (float*)(ws + AGG_OFF);
    ushort_t* node_bf = (ushort_t*)(ws + NB_OFF);
    ushort_t* wimg    = (ushort_t*)(ws + WIMG_OFF);
    ushort_t* wuimg   = (ushort_t*)(ws + WUIMG_OFF);

    ushort_t* wm   = wimg;                 // 21504 B
    ushort_t* wa   = wimg + 10752;         // +21504 B
    ushort_t* w2s  = wimg + 21504;         // +8192 B
    ushort_t* wu1t = wuimg;                // 17408 B
    ushort_t* wu2t = wuimg + 8704;         // +9216 B

    k_prep_node<<<(N_NODES_C * 64 / 8 + 255) / 256, 256, 0, stream>>>(node, node_bf, expsum);
    k_prep_w<<<76, 256, 0, stream>>>(W1, Wa1, W2, Wu1, Wu2, wm, wa, w2s, wu1t, wu2t);
    k_edge<<<N_BLOCKS, 256, 0, stream>>>(node_bf, edgef, senders, receivers,
                                         wimg, b1, ba1, Wa2, ba2, b2, expsum, agg);
    k_upd<<<(N_NODES_C + 127) / 128, 256, 0, stream>>>(node_bf, agg, wuimg,
                                                       bu1, bu2, expsum, out);
}